// Round 1
// baseline (12335.468 us; speedup 1.0000x reference)
//
#include <hip/hip_runtime.h>
#include <hip/hip_bf16.h>
#include <float.h>

// Problem constants (fixed by setup_inputs): B=16, L=256, D=128.
#define B_SZ 16
#define L_SZ 256
#define D_SZ 128

// ---------------------------------------------------------------------------
// Kernel 1: pairwise L2 distance. dist[b][i][j] = || pred[b,i,:] - target[b,j,:] ||_2
// Block = (batch b, tile of 8 rows i). 256 threads; thread j owns column j.
// Pred tile staged in LDS (broadcast reads); target row streamed as float4.
// ---------------------------------------------------------------------------
__global__ __launch_bounds__(256) void dist_kernel(const float* __restrict__ pred,
                                                   const float* __restrict__ target,
                                                   float* __restrict__ dist) {
    __shared__ float predRows[8][D_SZ];
    const int blk = blockIdx.x;          // 0 .. B*L/8-1  (512)
    const int b   = blk >> 5;            // 32 blocks per batch
    const int i0  = (blk & 31) * 8;
    const int tid = threadIdx.x;

    for (int idx = tid; idx < 8 * D_SZ; idx += 256) {
        int r = idx >> 7, d = idx & (D_SZ - 1);
        predRows[r][d] = pred[((size_t)b * L_SZ + i0 + r) * D_SZ + d];
    }
    __syncthreads();

    const int j = tid;
    const float* tr = target + ((size_t)b * L_SZ + j) * D_SZ;
    float acc[8];
#pragma unroll
    for (int r = 0; r < 8; ++r) acc[r] = 0.0f;

    for (int d = 0; d < D_SZ; d += 4) {
        float4 tv = *(const float4*)(tr + d);
#pragma unroll
        for (int r = 0; r < 8; ++r) {
            float4 pv = *(const float4*)(&predRows[r][d]);  // ds_read_b128 broadcast
            float dx = pv.x - tv.x; acc[r] += dx * dx;
            float dy = pv.y - tv.y; acc[r] += dy * dy;
            float dz = pv.z - tv.z; acc[r] += dz * dz;
            float dw = pv.w - tv.w; acc[r] += dw * dw;
        }
    }
#pragma unroll
    for (int r = 0; r < 8; ++r)
        dist[((size_t)b * L_SZ + i0 + r) * L_SZ + j] = sqrtf(acc[r]);
}

// ---------------------------------------------------------------------------
// Kernel 2: exact Jonker-Volgenant LSA, one batch per block, one wave (64
// lanes) per block, lane t owns columns 4t..4t+3 (1-based 4t+1..4t+4).
// All arithmetic in double to match the numpy float64 reference exactly
// (including np.argmin lowest-index tie-breaking).
// ---------------------------------------------------------------------------
#define INF_D 1e300

__device__ inline void argmin_wave(double& val, int& idx) {
#pragma unroll
    for (int off = 1; off < 64; off <<= 1) {
        double ov = __shfl_xor(val, off, 64);
        int    oi = __shfl_xor(idx, off, 64);
        if (ov < val || (ov == val && oi < idx)) { val = ov; idx = oi; }
    }
}

__global__ __launch_bounds__(64) void lsa_kernel(const float* __restrict__ dist,
                                                 double* __restrict__ partial) {
    const int n = L_SZ;
    __shared__ double u[L_SZ + 1];
    __shared__ double v[L_SZ + 1];
    __shared__ double minv[L_SZ + 1];
    __shared__ int    p[L_SZ + 1];
    __shared__ int    way[L_SZ + 1];
    __shared__ unsigned char used[L_SZ + 1];

    const int b = blockIdx.x;
    const int t = threadIdx.x;   // 0..63
    const float* cost = dist + (size_t)b * n * n;

    for (int idx = t; idx <= n; idx += 64) { u[idx] = 0.0; v[idx] = 0.0; p[idx] = 0; }
    __syncthreads();

    for (int i = 1; i <= n; ++i) {
        if (t == 0) p[0] = i;
        for (int idx = t; idx <= n; idx += 64) { minv[idx] = INF_D; used[idx] = 0; }
        __syncthreads();

        int j0 = 0;
        while (true) {
            if (t == 0) used[j0] = 1;
            __syncthreads();

            const int    i0  = p[j0];
            const double ui0 = u[i0];
            const float4 c4  = ((const float4*)(cost + (size_t)(i0 - 1) * n))[t];
            const double cs[4] = {(double)c4.x, (double)c4.y, (double)c4.z, (double)c4.w};

            double lv = INF_D * 10.0;
            int    lj = -1;
#pragma unroll
            for (int k = 0; k < 4; ++k) {
                const int jj = 4 * t + k + 1;
                if (!used[jj]) {
                    const double cur = cs[k] - ui0 - v[jj];
                    double m = minv[jj];
                    if (cur < m) { m = cur; minv[jj] = cur; way[jj] = j0; }
                    if (m < lv) { lv = m; lj = jj; }   // ascending k => first-min
                }
            }

            double delta = lv;
            int    j1    = lj;
            argmin_wave(delta, j1);
            __syncthreads();   // all minv/way writes visible; reductions done

            // potentials update: distinct LDS addresses per lane
#pragma unroll
            for (int k = 0; k < 4; ++k) {
                const int jj = 4 * t + k + 1;
                if (used[jj]) { u[p[jj]] += delta; v[jj] -= delta; }
                else          { minv[jj] -= delta; }
            }
            if (t == 0) { u[p[0]] += delta; v[0] -= delta; }
            __syncthreads();

            j0 = j1;
            if (p[j0] == 0) break;
        }

        // augment along way[] — serial, lane 0
        if (t == 0) {
            int j = j0;
            while (j != 0) { int jn = way[j]; p[j] = p[jn]; j = jn; }
        }
        __syncthreads();
    }

    // partial sum of matched fp32 distances: column j matched to row p[j]-1
    double s = 0.0;
#pragma unroll
    for (int k = 0; k < 4; ++k) {
        const int jj = 4 * t + k + 1;
        const int r  = p[jj] - 1;
        s += (double)cost[(size_t)r * n + (jj - 1)];
    }
#pragma unroll
    for (int off = 1; off < 64; off <<= 1) s += __shfl_xor(s, off, 64);
    if (t == 0) partial[b] = s;
}

// ---------------------------------------------------------------------------
// Kernel 3: final mean
// ---------------------------------------------------------------------------
__global__ void finalize_kernel(const double* __restrict__ partial, float* __restrict__ out) {
    double s = 0.0;
    for (int b = 0; b < B_SZ; ++b) s += partial[b];
    out[0] = (float)(s / (double)(B_SZ * L_SZ));
}

extern "C" void kernel_launch(void* const* d_in, const int* in_sizes, int n_in,
                              void* d_out, int out_size, void* d_ws, size_t ws_size,
                              hipStream_t stream) {
    const float* pred   = (const float*)d_in[0];
    const float* target = (const float*)d_in[1];
    float* out = (float*)d_out;

    float*  dist    = (float*)d_ws;
    double* partial = (double*)((char*)d_ws + (size_t)B_SZ * L_SZ * L_SZ * sizeof(float));

    dist_kernel<<<B_SZ * L_SZ / 8, 256, 0, stream>>>(pred, target, dist);
    lsa_kernel<<<B_SZ, 64, 0, stream>>>(dist, partial);
    finalize_kernel<<<1, 1, 0, stream>>>(partial, out);
}

// Round 2
// 3214.353 us; speedup vs baseline: 3.8376x; 3.8376x over previous
//
#include <hip/hip_runtime.h>
#include <hip/hip_fp16.h>
#include <hip/hip_bf16.h>
#include <float.h>

// Problem constants (fixed by setup_inputs): B=16, L=256, D=128.
#define B_SZ 16
#define L_SZ 256
#define D_SZ 128

// ---------------------------------------------------------------------------
// Kernel 1: pairwise L2 distance (unchanged from R1 — not on critical path).
// ---------------------------------------------------------------------------
__global__ __launch_bounds__(256) void dist_kernel(const float* __restrict__ pred,
                                                   const float* __restrict__ target,
                                                   float* __restrict__ dist) {
    __shared__ float predRows[8][D_SZ];
    const int blk = blockIdx.x;
    const int b   = blk >> 5;
    const int i0  = (blk & 31) * 8;
    const int tid = threadIdx.x;

    for (int idx = tid; idx < 8 * D_SZ; idx += 256) {
        int r = idx >> 7, d = idx & (D_SZ - 1);
        predRows[r][d] = pred[((size_t)b * L_SZ + i0 + r) * D_SZ + d];
    }
    __syncthreads();

    const int j = tid;
    const float* tr = target + ((size_t)b * L_SZ + j) * D_SZ;
    float acc[8];
#pragma unroll
    for (int r = 0; r < 8; ++r) acc[r] = 0.0f;

    for (int d = 0; d < D_SZ; d += 4) {
        float4 tv = *(const float4*)(tr + d);
#pragma unroll
        for (int r = 0; r < 8; ++r) {
            float4 pv = *(const float4*)(&predRows[r][d]);
            float dx = pv.x - tv.x; acc[r] += dx * dx;
            float dy = pv.y - tv.y; acc[r] += dy * dy;
            float dz = pv.z - tv.z; acc[r] += dz * dz;
            float dw = pv.w - tv.w; acc[r] += dw * dw;
        }
    }
#pragma unroll
    for (int r = 0; r < 8; ++r)
        dist[((size_t)b * L_SZ + i0 + r) * L_SZ + j] = sqrtf(acc[r]);
}

// ---------------------------------------------------------------------------
// Kernel 2: JV LSA, Dijkstra formulation with phase-start potentials.
// One batch per block, one wave per block, lane t owns columns 4t+1..4t+4
// (1-based). Per-column state in registers; cost matrix fp16 in LDS;
// u[] (per-row potential) in LDS; argmin via DPP min-reduce.
// ---------------------------------------------------------------------------
__device__ inline unsigned sortable_f32(float f) {
    unsigned u = __float_as_uint(f);
    return u ^ (unsigned)(((int)u >> 31) | 0x80000000);
}
__device__ inline float unsortable_f32(unsigned s) {
    unsigned u = (s & 0x80000000u) ? (s ^ 0x80000000u) : ~s;
    return __uint_as_float(u);
}

// One min-reduce step via DPP: (val,idx) <- min with permuted lane, tie -> lower idx.
// bound_ctrl=false + old=own value => invalid source lanes are a no-op.
template <int CTRL>
__device__ inline void dpp_min_step(unsigned& val, unsigned& idx) {
    unsigned pv = (unsigned)__builtin_amdgcn_update_dpp((int)val, (int)val, CTRL, 0xF, 0xF, false);
    unsigned pi = (unsigned)__builtin_amdgcn_update_dpp((int)idx, (int)idx, CTRL, 0xF, 0xF, false);
    bool lt = (pv < val) || ((pv == val) && (pi < idx));
    val = lt ? pv : val;
    idx = lt ? pi : idx;
}

#define LSA_LDS_BYTES (L_SZ * L_SZ * 2 + (L_SZ + 1) * 4 + 4)

__global__ __launch_bounds__(64) void lsa_kernel(const float* __restrict__ dist,
                                                 double* __restrict__ partial) {
    extern __shared__ char smem[];
    __half* cost_h = (__half*)smem;                       // 256x256 fp16, row-major
    float*  u_lds  = (float*)(smem + L_SZ * L_SZ * 2);    // u[0..256]

    const int b = blockIdx.x;
    const int t = threadIdx.x;  // 0..63
    const float* cost = dist + (size_t)b * L_SZ * L_SZ;

    // ---- prologue: stage cost as fp16 in LDS; zero u ----
    for (int idx = t * 4; idx < L_SZ * L_SZ; idx += 64 * 4) {
        float4 f = *(const float4*)(cost + idx);
        union { unsigned u; __half2 h; } a, c;
        a.h = __floats2half2_rn(f.x, f.y);
        c.h = __floats2half2_rn(f.z, f.w);
        uint2 pk; pk.x = a.u; pk.y = c.u;
        *(uint2*)(&cost_h[idx]) = pk;
    }
    for (int idx = t; idx <= L_SZ; idx += 64) u_lds[idx] = 0.0f;
    __syncthreads();

    // ---- per-lane column state (columns jj = 4t+1 .. 4t+4, 1-based) ----
    float v0 = 0.f, v1 = 0.f, v2 = 0.f, v3 = 0.f;        // column potentials
    int   p0 = 0,   p1 = 0,   p2 = 0,   p3 = 0;          // matched row (0 = free)
    float pu0 = 0.f, pu1 = 0.f, pu2 = 0.f, pu3 = 0.f;    // u[p[j]] cache
    const int jjA = 4 * t + 1, jjB = 4 * t + 2, jjC = 4 * t + 3, jjD = 4 * t + 4;

    for (int icur = 1; icur <= L_SZ; ++icur) {
        float d0 = FLT_MAX, d1 = FLT_MAX, d2 = FLT_MAX, d3 = FLT_MAX;  // Dijkstra dists
        int   w0 = 0, w1 = 0, w2 = 0, w3 = 0;                          // way[]
        int   um = 0;                                                  // used bitmask
        int   i0  = icur;
        float ui0 = u_lds[icur];
        float dj0 = 0.f;
        int   j0  = 0;
        int   jS; float dfin;

        while (true) {
            // relax all columns from row i0 (cost row from LDS, fp16)
            uint2 cpk = *(const uint2*)(smem + (size_t)(i0 - 1) * (L_SZ * 2) + t * 8);
            union { unsigned u; __half2 h; } ca, cb;
            ca.u = cpk.x; cb.u = cpk.y;
            float c0 = __low2float(ca.h), c1 = __high2float(ca.h);
            float c2 = __low2float(cb.h), c3 = __high2float(cb.h);
            float base = dj0 - ui0;
            float n0 = base + (c0 - v0);
            float n1 = base + (c1 - v1);
            float n2 = base + (c2 - v2);
            float n3 = base + (c3 - v3);
            if (!(um & 1) && (n0 < d0)) { d0 = n0; w0 = j0; }
            if (!(um & 2) && (n1 < d1)) { d1 = n1; w1 = j0; }
            if (!(um & 4) && (n2 < d2)) { d2 = n2; w2 = j0; }
            if (!(um & 8) && (n3 < d3)) { d3 = n3; w3 = j0; }

            // wave argmin over free columns: packed (sortable value, column idx)
            unsigned s0 = (um & 1) ? 0xFFFFFFFFu : sortable_f32(d0);
            unsigned s1 = (um & 2) ? 0xFFFFFFFFu : sortable_f32(d1);
            unsigned s2 = (um & 4) ? 0xFFFFFFFFu : sortable_f32(d2);
            unsigned s3 = (um & 8) ? 0xFFFFFFFFu : sortable_f32(d3);
            unsigned val = s0, idx = (unsigned)jjA;
            if (s1 < val) { val = s1; idx = (unsigned)jjB; }
            if (s2 < val) { val = s2; idx = (unsigned)jjC; }
            if (s3 < val) { val = s3; idx = (unsigned)jjD; }
            dpp_min_step<0x111>(val, idx);  // row_shr:1
            dpp_min_step<0x112>(val, idx);  // row_shr:2
            dpp_min_step<0x114>(val, idx);  // row_shr:4
            dpp_min_step<0x118>(val, idx);  // row_shr:8
            dpp_min_step<0x142>(val, idx);  // row_bcast15
            dpp_min_step<0x143>(val, idx);  // row_bcast31
            unsigned smin = (unsigned)__builtin_amdgcn_readlane((int)val, 63);
            int      j1   = __builtin_amdgcn_readlane((int)idx, 63);
            float    delta = unsortable_f32(smin);

            // settle j1: fetch its matched row and that row's u (register shuffle)
            int t1 = (j1 - 1) >> 2, k1 = (j1 - 1) & 3;
            int   psel  = (k1 == 0) ? p0 : (k1 == 1) ? p1 : (k1 == 2) ? p2 : p3;
            float pusel = (k1 == 0) ? pu0 : (k1 == 1) ? pu1 : (k1 == 2) ? pu2 : pu3;
            int   i1 = __builtin_amdgcn_readlane(psel, t1);
            float u1 = __uint_as_float((unsigned)__builtin_amdgcn_readlane((int)__float_as_uint(pusel), t1));
            if (i1 == 0) { jS = j1; dfin = delta; break; }   // free column: path found
            if (t == t1) um |= (1 << k1);
            j0 = j1; dj0 = delta; i0 = i1; ui0 = u1;
        }

        // ---- phase end: potential updates (pre-augment p gives settled rows) ----
        if (um & 1) { u_lds[p0] += dfin - d0; v0 += d0 - dfin; }
        if (um & 2) { u_lds[p1] += dfin - d1; v1 += d1 - dfin; }
        if (um & 4) { u_lds[p2] += dfin - d2; v2 += d2 - dfin; }
        if (um & 8) { u_lds[p3] += dfin - d3; v3 += d3 - dfin; }
        if (t == 0) u_lds[icur] += dfin;
        __syncthreads();

        // ---- augment along way[] (wave-uniform walk over register state) ----
        int j = jS;
        while (true) {
            int tj = (j - 1) >> 2, kj = (j - 1) & 3;
            int wsel = (kj == 0) ? w0 : (kj == 1) ? w1 : (kj == 2) ? w2 : w3;
            int jn = __builtin_amdgcn_readlane(wsel, tj);
            int pn;
            if (jn == 0) pn = icur;
            else {
                int tn = (jn - 1) >> 2, kn = (jn - 1) & 3;
                int ps2 = (kn == 0) ? p0 : (kn == 1) ? p1 : (kn == 2) ? p2 : p3;
                pn = __builtin_amdgcn_readlane(ps2, tn);
            }
            if (t == tj) {
                if (kj == 0) p0 = pn; else if (kj == 1) p1 = pn;
                else if (kj == 2) p2 = pn; else p3 = pn;
            }
            if (jn == 0) break;
            j = jn;
        }

        // refresh u[p[j]] caches (p==0 reads u_lds[0]: harmless, value unused)
        pu0 = u_lds[p0]; pu1 = u_lds[p1]; pu2 = u_lds[p2]; pu3 = u_lds[p3];
        __syncthreads();
    }

    // ---- matched sum from ORIGINAL fp32 distances ----
    double s = 0.0;
    s += (double)cost[(size_t)(p0 - 1) * L_SZ + (jjA - 1)];
    s += (double)cost[(size_t)(p1 - 1) * L_SZ + (jjB - 1)];
    s += (double)cost[(size_t)(p2 - 1) * L_SZ + (jjC - 1)];
    s += (double)cost[(size_t)(p3 - 1) * L_SZ + (jjD - 1)];
#pragma unroll
    for (int off = 1; off < 64; off <<= 1) s += __shfl_xor(s, off, 64);
    if (t == 0) partial[b] = s;
}

// ---------------------------------------------------------------------------
// Kernel 3: final mean
// ---------------------------------------------------------------------------
__global__ void finalize_kernel(const double* __restrict__ partial, float* __restrict__ out) {
    double s = 0.0;
    for (int b = 0; b < B_SZ; ++b) s += partial[b];
    out[0] = (float)(s / (double)(B_SZ * L_SZ));
}

extern "C" void kernel_launch(void* const* d_in, const int* in_sizes, int n_in,
                              void* d_out, int out_size, void* d_ws, size_t ws_size,
                              hipStream_t stream) {
    const float* pred   = (const float*)d_in[0];
    const float* target = (const float*)d_in[1];
    float* out = (float*)d_out;

    float*  dist    = (float*)d_ws;
    double* partial = (double*)((char*)d_ws + (size_t)B_SZ * L_SZ * L_SZ * sizeof(float));

    // opt-in to >64KB dynamic LDS (idempotent; not a stream op, capture-safe)
    (void)hipFuncSetAttribute((const void*)lsa_kernel,
                              hipFuncAttributeMaxDynamicSharedMemorySize,
                              LSA_LDS_BYTES);

    dist_kernel<<<B_SZ * L_SZ / 8, 256, 0, stream>>>(pred, target, dist);
    lsa_kernel<<<B_SZ, 64, LSA_LDS_BYTES, stream>>>(dist, partial);
    finalize_kernel<<<1, 1, 0, stream>>>(partial, out);
}

// Round 3
// 2230.022 us; speedup vs baseline: 5.5315x; 1.4414x over previous
//
#include <hip/hip_runtime.h>
#include <hip/hip_fp16.h>
#include <hip/hip_bf16.h>
#include <float.h>
#include <limits.h>

// Problem constants (fixed by setup_inputs): B=16, L=256, D=128.
#define B_SZ 16
#define L_SZ 256
#define D_SZ 128

// ---------------------------------------------------------------------------
// Kernel 1: pairwise L2 distance (unchanged — not on critical path).
// ---------------------------------------------------------------------------
__global__ __launch_bounds__(256) void dist_kernel(const float* __restrict__ pred,
                                                   const float* __restrict__ target,
                                                   float* __restrict__ dist) {
    __shared__ float predRows[8][D_SZ];
    const int blk = blockIdx.x;
    const int b   = blk >> 5;
    const int i0  = (blk & 31) * 8;
    const int tid = threadIdx.x;

    for (int idx = tid; idx < 8 * D_SZ; idx += 256) {
        int r = idx >> 7, d = idx & (D_SZ - 1);
        predRows[r][d] = pred[((size_t)b * L_SZ + i0 + r) * D_SZ + d];
    }
    __syncthreads();

    const int j = tid;
    const float* tr = target + ((size_t)b * L_SZ + j) * D_SZ;
    float acc[8];
#pragma unroll
    for (int r = 0; r < 8; ++r) acc[r] = 0.0f;

    for (int d = 0; d < D_SZ; d += 4) {
        float4 tv = *(const float4*)(tr + d);
#pragma unroll
        for (int r = 0; r < 8; ++r) {
            float4 pv = *(const float4*)(&predRows[r][d]);
            float dx = pv.x - tv.x; acc[r] += dx * dx;
            float dy = pv.y - tv.y; acc[r] += dy * dy;
            float dz = pv.z - tv.z; acc[r] += dz * dz;
            float dw = pv.w - tv.w; acc[r] += dw * dw;
        }
    }
#pragma unroll
    for (int r = 0; r < 8; ++r)
        dist[((size_t)b * L_SZ + i0 + r) * L_SZ + j] = sqrtf(acc[r]);
}

// ---------------------------------------------------------------------------
// Kernel 2: JV LSA with full initialization (col reduction + greedy + ARR)
// and packed single-word DPP argmin in the shortest-path phases.
// One batch per block, one wave; lane t owns 0-based columns 4t..4t+3.
// ---------------------------------------------------------------------------
__device__ inline unsigned sortable_f32(float f) {
    unsigned u = __float_as_uint(f);
    return u ^ (unsigned)(((int)u >> 31) | 0x80000000);
}
__device__ inline int readlane_i(int x, int l) { return __builtin_amdgcn_readlane(x, l); }
__device__ inline float readlane_f(float x, int l) {
    return __uint_as_float((unsigned)__builtin_amdgcn_readlane((int)__float_as_uint(x), l));
}
template <int CTRL>
__device__ inline unsigned dpp_umin(unsigned v) {
    unsigned pv = (unsigned)__builtin_amdgcn_update_dpp((int)v, (int)v, CTRL, 0xF, 0xF, false);
    return pv < v ? pv : v;
}
__device__ inline unsigned wave_umin_bcast(unsigned v) {
    v = dpp_umin<0x111>(v);   // row_shr:1
    v = dpp_umin<0x112>(v);   // row_shr:2
    v = dpp_umin<0x114>(v);   // row_shr:4
    v = dpp_umin<0x118>(v);   // row_shr:8
    v = dpp_umin<0x142>(v);   // row_bcast15
    v = dpp_umin<0x143>(v);   // row_bcast31
    return (unsigned)__builtin_amdgcn_readlane((int)v, 63);
}
__device__ inline void unpack4(uint2 pk, float& a, float& b, float& c, float& d) {
    union { unsigned u; __half2 h; } x, y; x.u = pk.x; y.u = pk.y;
    a = __low2float(x.h); b = __high2float(x.h);
    c = __low2float(y.h); d = __high2float(y.h);
}
#define SEL4(a0,a1,a2,a3,k) ((k)==0?(a0):(k)==1?(a1):(k)==2?(a2):(a3))

#define OFF_U      (L_SZ * L_SZ * 2)                 // fp16 matrix: 131072 B
#define OFF_CLAIM  (OFF_U + (L_SZ + 1) * 4)
#define OFF_FL     (OFF_CLAIM + (L_SZ + 1) * 4)
#define LSA_LDS_BYTES (OFF_FL + (L_SZ + 1) * 4 + 4)  // 134160

__global__ __launch_bounds__(64) void lsa_kernel(const float* __restrict__ dist,
                                                 double* __restrict__ partial) {
    extern __shared__ char smem[];
    float* u_lds   = (float*)(smem + OFF_U);
    int*   claimed = (int*)(smem + OFF_CLAIM);
    int*   fl      = (int*)(smem + OFF_FL);

    const int b = blockIdx.x;
    const int t = threadIdx.x;  // 0..63
    const float* cost = dist + (size_t)b * L_SZ * L_SZ;
    const int c0i = 4 * t, c1i = 4 * t + 1, c2i = 4 * t + 2, c3i = 4 * t + 3;

    // ---- stage cost as fp16 in LDS ----
    for (int idx = t * 4; idx < L_SZ * L_SZ; idx += 256) {
        float4 f = *(const float4*)(cost + idx);
        union { unsigned u; __half2 h; } a, c;
        a.h = __floats2half2_rn(f.x, f.y);
        c.h = __floats2half2_rn(f.z, f.w);
        uint2 pk; pk.x = a.u; pk.y = c.u;
        *(uint2*)(smem + idx * 2) = pk;
    }
    __syncthreads();

    // ---- column reduction: v[j] = min_i c[i][j] (fp16-space, consistent) ----
    float bv0 = FLT_MAX, bv1 = FLT_MAX, bv2 = FLT_MAX, bv3 = FLT_MAX;
    int   br0 = 0, br1 = 0, br2 = 0, br3 = 0;
    for (int i = 1; i <= L_SZ; ++i) {
        uint2 cpk = *(const uint2*)(smem + (size_t)(i - 1) * (L_SZ * 2) + t * 8);
        float c0, c1, c2, c3; unpack4(cpk, c0, c1, c2, c3);
        if (c0 < bv0) { bv0 = c0; br0 = i; }
        if (c1 < bv1) { bv1 = c1; br1 = i; }
        if (c2 < bv2) { bv2 = c2; br2 = i; }
        if (c3 < bv3) { bv3 = c3; br3 = i; }
    }
    float v0 = bv0, v1 = bv1, v2 = bv2, v3 = bv3;

    // ---- greedy tight-edge matching via atomicMin claims ----
    for (int r = t; r <= L_SZ; r += 64) claimed[r] = INT_MAX;
    __syncthreads();
    atomicMin(&claimed[br0], c0i);
    atomicMin(&claimed[br1], c1i);
    atomicMin(&claimed[br2], c2i);
    atomicMin(&claimed[br3], c3i);
    __syncthreads();
    int p0 = (claimed[br0] == c0i) ? br0 : 0;
    int p1 = (claimed[br1] == c1i) ? br1 : 0;
    int p2 = (claimed[br2] == c2i) ? br2 : 0;
    int p3 = (claimed[br3] == c3i) ? br3 : 0;

    // ---- deterministic free-row list (ballot scan) ----
    int nf = 0;
    for (int blk = 0; blk < 4; ++blk) {
        int r = blk * 64 + t + 1;
        bool isfree = (claimed[r] == INT_MAX);
        unsigned long long mask = __ballot(isfree);
        int before = __popcll(mask & ((1ULL << t) - 1ULL));
        if (isfree) fl[nf + before] = r;
        nf += (int)__popcll(mask);
    }
    __syncthreads();

    // ---- augmenting row reduction (lap.cpp, 2 passes, budget-guarded) ----
    int numfree = nf;
    int budget = 1024;
    for (int pass = 0; pass < 2; ++pass) {
        int kq = 0, prv = numfree; numfree = 0;
        while (kq < prv && budget > 0) {
            budget--;
            int i = fl[kq]; kq++;
            uint2 cpk = *(const uint2*)(smem + (size_t)(i - 1) * (L_SZ * 2) + t * 8);
            float cc0, cc1, cc2, cc3; unpack4(cpk, cc0, cc1, cc2, cc3);
            float rc0 = cc0 - v0, rc1 = cc1 - v1, rc2 = cc2 - v2, rc3 = cc3 - v3;
            float m1 = rc0; int j1 = c0i; float m2 = FLT_MAX; int j2 = INT_MAX;
            if (rc1 < m1) { m2 = m1; j2 = j1; m1 = rc1; j1 = c1i; } else if (rc1 < m2) { m2 = rc1; j2 = c1i; }
            if (rc2 < m1) { m2 = m1; j2 = j1; m1 = rc2; j1 = c2i; } else if (rc2 < m2) { m2 = rc2; j2 = c2i; }
            if (rc3 < m1) { m2 = m1; j2 = j1; m1 = rc3; j1 = c3i; } else if (rc3 < m2) { m2 = rc3; j2 = c3i; }
            // top-2 xor-butterfly merge (total order on (m,j) -> associative,
            // all lanes converge to identical results)
#pragma unroll
            for (int off = 1; off < 64; off <<= 1) {
                float bm1 = __shfl_xor(m1, off, 64); int bj1 = __shfl_xor(j1, off, 64);
                float bm2 = __shfl_xor(m2, off, 64); int bj2 = __shfl_xor(j2, off, 64);
                bool bw = (bm1 < m1) || (bm1 == m1 && bj1 < j1);
                if (bw) {
                    if (bm2 < m1 || (bm2 == m1 && bj2 < j1)) { m2 = bm2; j2 = bj2; }
                    else { m2 = m1; j2 = j1; }
                    m1 = bm1; j1 = bj1;
                } else {
                    if (bm1 < m2 || (bm1 == m2 && bj1 < j2)) { m2 = bm1; j2 = bj1; }
                }
            }
            int t1 = j1 >> 2, k1 = j1 & 3;
            int i0 = readlane_i(SEL4(p0, p1, p2, p3, k1), t1);
            bool strict = (m1 < m2);
            int jt, i0t;
            if (strict) {
                jt = j1; i0t = i0;
                float amt = m2 - m1;
                if (t == t1) {
                    if (k1 == 0) v0 -= amt; else if (k1 == 1) v1 -= amt;
                    else if (k1 == 2) v2 -= amt; else v3 -= amt;
                }
            } else if (i0 != 0) {
                jt = j2; i0t = readlane_i(SEL4(p0, p1, p2, p3, j2 & 3), j2 >> 2);
            } else { jt = j1; i0t = 0; }
            {
                int tt = jt >> 2, kk = jt & 3;
                if (t == tt) {
                    if (kk == 0) p0 = i; else if (kk == 1) p1 = i;
                    else if (kk == 2) p2 = i; else p3 = i;
                }
            }
            if (i0t != 0) {
                if (strict) { kq--; if (t == 0) fl[kq] = i0t; }
                else        { if (t == 0) fl[numfree] = i0t; numfree++; }
            }
            __syncthreads();
        }
        if (budget <= 0) break;
    }

    // ---- rebuild free-row list from scratch; init u (tight duals) ----
    __syncthreads();
    for (int r = t; r <= L_SZ; r += 64) { claimed[r] = 0; u_lds[r] = 0.0f; }
    __syncthreads();
    if (p0) claimed[p0] = 1;
    if (p1) claimed[p1] = 1;
    if (p2) claimed[p2] = 1;
    if (p3) claimed[p3] = 1;
    __syncthreads();
    int nfree = 0;
    for (int blk = 0; blk < 4; ++blk) {
        int r = blk * 64 + t + 1;
        bool isfree = (claimed[r] == 0);
        unsigned long long mask = __ballot(isfree);
        int before = __popcll(mask & ((1ULL << t) - 1ULL));
        if (isfree) fl[nfree + before] = r;
        nfree += (int)__popcll(mask);
    }
    __syncthreads();
    float pu0 = 0.f, pu1 = 0.f, pu2 = 0.f, pu3 = 0.f;
    const __half* ch = (const __half*)smem;
    if (p0) { pu0 = __half2float(ch[(size_t)(p0 - 1) * L_SZ + c0i]) - v0; u_lds[p0] = pu0; }
    if (p1) { pu1 = __half2float(ch[(size_t)(p1 - 1) * L_SZ + c1i]) - v1; u_lds[p1] = pu1; }
    if (p2) { pu2 = __half2float(ch[(size_t)(p2 - 1) * L_SZ + c2i]) - v2; u_lds[p2] = pu2; }
    if (p3) { pu3 = __half2float(ch[(size_t)(p3 - 1) * L_SZ + c3i]) - v3; u_lds[p3] = pu3; }
    __syncthreads();

    // ---- shortest-path phases for remaining free rows ----
    for (int f = 0; f < nfree; ++f) {
        int icur = fl[f];
        float d0 = FLT_MAX, d1 = FLT_MAX, d2 = FLT_MAX, d3 = FLT_MAX;
        int w0 = -1, w1 = -1, w2 = -1, w3 = -1, um = 0;
        int i0 = icur; float ui0 = u_lds[icur]; float dj0 = 0.f; int j0 = -1;
        int jS = 0; float dfin = 0.f;
        for (int it = 0; it <= L_SZ; ++it) {
            uint2 cpk = *(const uint2*)(smem + (size_t)(i0 - 1) * (L_SZ * 2) + t * 8);
            float cc0, cc1, cc2, cc3; unpack4(cpk, cc0, cc1, cc2, cc3);
            float base = dj0 - ui0;
            float n0 = base + (cc0 - v0);
            float n1 = base + (cc1 - v1);
            float n2 = base + (cc2 - v2);
            float n3 = base + (cc3 - v3);
            if (!(um & 1) && n0 < d0) { d0 = n0; w0 = j0; }
            if (!(um & 2) && n1 < d1) { d1 = n1; w1 = j0; }
            if (!(um & 4) && n2 < d2) { d2 = n2; w2 = j0; }
            if (!(um & 8) && n3 < d3) { d3 = n3; w3 = j0; }

            unsigned s0 = (um & 1) ? 0xFFFFFFFFu : ((sortable_f32(d0) & 0xFFFFFF00u) | (unsigned)c0i);
            unsigned s1 = (um & 2) ? 0xFFFFFFFFu : ((sortable_f32(d1) & 0xFFFFFF00u) | (unsigned)c1i);
            unsigned s2 = (um & 4) ? 0xFFFFFFFFu : ((sortable_f32(d2) & 0xFFFFFF00u) | (unsigned)c2i);
            unsigned s3 = (um & 8) ? 0xFFFFFFFFu : ((sortable_f32(d3) & 0xFFFFFF00u) | (unsigned)c3i);
            unsigned va = s0 < s1 ? s0 : s1;
            unsigned vb = s2 < s3 ? s2 : s3;
            unsigned pk = wave_umin_bcast(va < vb ? va : vb);
            int j1 = (int)(pk & 255u);
            int t1 = j1 >> 2, k1 = j1 & 3;
            float delta = readlane_f(SEL4(d0, d1, d2, d3, k1), t1);
            int   i1    = readlane_i(SEL4(p0, p1, p2, p3, k1), t1);
            float u1    = readlane_f(SEL4(pu0, pu1, pu2, pu3, k1), t1);
            if (i1 == 0 || it == L_SZ) { jS = j1; dfin = delta; break; }
            if (t == t1) um |= (1 << k1);
            j0 = j1; dj0 = delta; i0 = i1; ui0 = u1;
        }
        if (um & 1) { u_lds[p0] += dfin - d0; v0 += d0 - dfin; }
        if (um & 2) { u_lds[p1] += dfin - d1; v1 += d1 - dfin; }
        if (um & 4) { u_lds[p2] += dfin - d2; v2 += d2 - dfin; }
        if (um & 8) { u_lds[p3] += dfin - d3; v3 += d3 - dfin; }
        if (t == 0) u_lds[icur] += dfin;
        __syncthreads();

        // augment along way[]
        int j = jS;
        for (int st = 0; st <= L_SZ; ++st) {
            int tj = j >> 2, kj = j & 3;
            int jn = readlane_i(SEL4(w0, w1, w2, w3, kj), tj);
            int pn;
            if (jn < 0) pn = icur;
            else pn = readlane_i(SEL4(p0, p1, p2, p3, jn & 3), jn >> 2);
            if (t == tj) {
                if (kj == 0) p0 = pn; else if (kj == 1) p1 = pn;
                else if (kj == 2) p2 = pn; else p3 = pn;
            }
            if (jn < 0) break;
            j = jn;
        }
        pu0 = u_lds[p0]; pu1 = u_lds[p1]; pu2 = u_lds[p2]; pu3 = u_lds[p3];
        __syncthreads();
    }

    // ---- matched sum from ORIGINAL fp32 distances ----
    double s = 0.0;
    s += (double)cost[(size_t)(p0 - 1) * L_SZ + c0i];
    s += (double)cost[(size_t)(p1 - 1) * L_SZ + c1i];
    s += (double)cost[(size_t)(p2 - 1) * L_SZ + c2i];
    s += (double)cost[(size_t)(p3 - 1) * L_SZ + c3i];
#pragma unroll
    for (int off = 1; off < 64; off <<= 1) s += __shfl_xor(s, off, 64);
    if (t == 0) partial[b] = s;
}

// ---------------------------------------------------------------------------
// Kernel 3: final mean
// ---------------------------------------------------------------------------
__global__ void finalize_kernel(const double* __restrict__ partial, float* __restrict__ out) {
    double s = 0.0;
    for (int b = 0; b < B_SZ; ++b) s += partial[b];
    out[0] = (float)(s / (double)(B_SZ * L_SZ));
}

extern "C" void kernel_launch(void* const* d_in, const int* in_sizes, int n_in,
                              void* d_out, int out_size, void* d_ws, size_t ws_size,
                              hipStream_t stream) {
    const float* pred   = (const float*)d_in[0];
    const float* target = (const float*)d_in[1];
    float* out = (float*)d_out;

    float*  dist    = (float*)d_ws;
    double* partial = (double*)((char*)d_ws + (size_t)B_SZ * L_SZ * L_SZ * sizeof(float));

    (void)hipFuncSetAttribute((const void*)lsa_kernel,
                              hipFuncAttributeMaxDynamicSharedMemorySize,
                              LSA_LDS_BYTES);

    dist_kernel<<<B_SZ * L_SZ / 8, 256, 0, stream>>>(pred, target, dist);
    lsa_kernel<<<B_SZ, 64, LSA_LDS_BYTES, stream>>>(dist, partial);
    finalize_kernel<<<1, 1, 0, stream>>>(partial, out);
}